// Round 1
// baseline (127.625 us; speedup 1.0000x reference)
//
#include <hip/hip_runtime.h>

// Problem constants (match reference)
constexpr int BB = 256;
constexpr int SS = 8192;
constexpr int NPOS = BB * SS;          // 2,097,152 positions
constexpr int IGNORE = -100;
constexpr int BLOCKS = NPOS / 4 / 256; // 2048 blocks, 4 positions/thread
// GAMMA = 2.0 -> (1-pt)^2

typedef float f32x4 __attribute__((ext_vector_type(4)));
typedef int   i32x4 __attribute__((ext_vector_type(4)));

template <typename T>
__device__ __forceinline__ T ntload(const T* p) {
    return __builtin_nontemporal_load(p);
}

// focal CE with shortened dependency chain:
//   ce = log(s) + (m - x);  pt = e_lab * rcp(s)   (rcp || log, not serial exp after)
__device__ __forceinline__ void focal_acc(float l0, float l1, float l2,
                                          int lab, float& fl, float& cnt) {
    if (lab == IGNORE) return;
    float m  = fmaxf(l0, fmaxf(l1, l2));
    float e0 = __expf(l0 - m), e1 = __expf(l1 - m), e2 = __expf(l2 - m);
    float s  = e0 + e1 + e2;
    float x  = (lab == 0) ? l0 : ((lab == 1) ? l1 : l2);
    float el = (lab == 0) ? e0 : ((lab == 1) ? e1 : e2);
    float ce = __logf(s) + (m - x);
    float pt = el * __builtin_amdgcn_rcpf(s);   // == exp(-ce), ~1 ulp
    float om = 1.0f - pt;
    fl  += om * om * ce;
    cnt += 1.0f;
}

__device__ __forceinline__ float bce_term(float z, float y) {
    // max(z,0) - z*y + log1p(exp(-|z|))
    return fmaxf(z, 0.0f) - z * y + __logf(1.0f + __expf(-fabsf(z)));
}

// ws layout: float partial[5][BLOCKS]  (5 * 2048 * 4B = 40 KB)
__global__ __launch_bounds__(256)
void main_kernel(const float* __restrict__ a_logits,
                 const float* __restrict__ o_logits,
                 const float* __restrict__ b_logits,
                 const int*   __restrict__ a_labels,
                 const int*   __restrict__ o_labels,
                 float*       __restrict__ partial) {
    int t = blockIdx.x * blockDim.x + threadIdx.x;   // [0, NPOS/4)
    float fl_a = 0.f, cnt_a = 0.f, fl_o = 0.f, cnt_o = 0.f, bce = 0.f;

    {
        int p0   = t * 4;                // first of 4 consecutive positions
        int lane = threadIdx.x & 63;

        // ---- issue ALL stream loads up front, nontemporal (read-once data) ----
        i32x4 al4 = ntload((const i32x4*)(a_labels + p0));
        i32x4 ol4 = ntload((const i32x4*)(o_labels + p0));
        const f32x4* ap = (const f32x4*)(a_logits + p0 * 3);
        const f32x4* op = (const f32x4*)(o_logits + p0 * 3);
        const f32x4* bp = (const f32x4*)(b_logits + p0 * 2);
        f32x4 A0 = ntload(ap),     A1 = ntload(ap + 1), A2 = ntload(ap + 2);
        f32x4 O0 = ntload(op),     O1 = ntload(op + 1), O2 = ntload(op + 2);
        f32x4 Z0 = ntload(bp),     Z1 = ntload(bp + 1);

        // next-label for position p0+3: lane+1's al4.x (rows are wave-aligned:
        // a row end only ever falls on lane 63's last position)
        int al_next = __shfl_down(al4[0], 1, 64);
        int ol_next = __shfl_down(ol4[0], 1, 64);
        if (lane == 63) {
            if (((p0 + 3) & (SS - 1)) != SS - 1) {
                al_next = a_labels[p0 + 4];
                ol_next = o_labels[p0 + 4];
            } else {
                al_next = -1;            // JAX concat(..., -1) sentinel
                ol_next = -1;
            }
        }
        int al[5] = {al4[0], al4[1], al4[2], al4[3], al_next};
        int ol[5] = {ol4[0], ol4[1], ol4[2], ol4[3], ol_next};

        float aL[12] = {A0[0], A0[1], A0[2], A0[3], A1[0], A1[1], A1[2], A1[3],
                        A2[0], A2[1], A2[2], A2[3]};
        float oL[12] = {O0[0], O0[1], O0[2], O0[3], O1[0], O1[1], O1[2], O1[3],
                        O2[0], O2[1], O2[2], O2[3]};
        float z[8]   = {Z0[0], Z0[1], Z0[2], Z0[3], Z1[0], Z1[1], Z1[2], Z1[3]};

        #pragma unroll
        for (int j = 0; j < 4; ++j) {
            focal_acc(aL[3*j], aL[3*j+1], aL[3*j+2], al[j], fl_a, cnt_a);
            focal_acc(oL[3*j], oL[3*j+1], oL[3*j+2], ol[j], fl_o, cnt_o);
            float ys = ((al[j] == 1) || (ol[j] == 1)) ? 1.0f : 0.0f;
            float ye = (((al[j] == 2) && (al[j+1] != 2)) ||
                        ((ol[j] == 2) && (ol[j+1] != 2))) ? 1.0f : 0.0f;
            bce += bce_term(z[2*j],     ys);
            bce += bce_term(z[2*j + 1], ye);
        }
    }

    // block reduction: wave64 shuffle -> LDS -> thread0 writes block partial
    float vals[5] = {fl_a, cnt_a, fl_o, cnt_o, bce};
    #pragma unroll
    for (int k = 0; k < 5; ++k) {
        float v = vals[k];
        #pragma unroll
        for (int o = 32; o > 0; o >>= 1) v += __shfl_down(v, o, 64);
        vals[k] = v;
    }
    __shared__ float lds[4 * 5];
    int lane = threadIdx.x & 63, wid = threadIdx.x >> 6;
    if (lane == 0) {
        #pragma unroll
        for (int k = 0; k < 5; ++k) lds[wid * 5 + k] = vals[k];
    }
    __syncthreads();
    if (threadIdx.x == 0) {
        #pragma unroll
        for (int k = 0; k < 5; ++k) {
            float s = lds[k] + lds[5 + k] + lds[10 + k] + lds[15 + k];
            partial[k * BLOCKS + blockIdx.x] = s;   // plane layout, no atomics
        }
    }
}

__global__ __launch_bounds__(1024)
void sent_final_kernel(const float* __restrict__ s_logits,
                       const int*   __restrict__ s_labels,
                       const float* __restrict__ partial,
                       float* __restrict__ out) {
    int tid = threadIdx.x;               // 1024 threads

    // --- reduce the 5 partial planes (2048 each, coalesced, 2 rounds) ---
    float acc[5];
    #pragma unroll
    for (int k = 0; k < 5; ++k) {
        float s = 0.f;
        #pragma unroll
        for (int i = 0; i < BLOCKS / 1024; ++i)     // 2 iters
            s += partial[k * BLOCKS + tid + i * 1024];
        acc[k] = s;
    }

    // --- sentiment CE (one element per thread, B=256) ---
    float ce = 0.f, cnt = 0.f;
    if (tid < BB) {
        int lab = s_labels[tid];
        if (lab != IGNORE) {
            float l0 = s_logits[3*tid], l1 = s_logits[3*tid+1], l2 = s_logits[3*tid+2];
            float m   = fmaxf(l0, fmaxf(l1, l2));
            float lse = m + __logf(__expf(l0-m) + __expf(l1-m) + __expf(l2-m));
            float x   = (lab == 0) ? l0 : ((lab == 1) ? l1 : l2);
            ce  = lse - x;
            cnt = 1.0f;
        }
    }

    float vals[7] = {acc[0], acc[1], acc[2], acc[3], acc[4], ce, cnt};
    #pragma unroll
    for (int k = 0; k < 7; ++k) {
        float v = vals[k];
        #pragma unroll
        for (int o = 32; o > 0; o >>= 1) v += __shfl_down(v, o, 64);
        vals[k] = v;
    }
    __shared__ float lds[16 * 7];
    int lane = threadIdx.x & 63, wid = threadIdx.x >> 6;
    if (lane == 0) {
        #pragma unroll
        for (int k = 0; k < 7; ++k) lds[wid * 7 + k] = vals[k];
    }
    __syncthreads();
    if (threadIdx.x == 0) {
        float tot[7];
        #pragma unroll
        for (int k = 0; k < 7; ++k) {
            float s = 0.f;
            #pragma unroll
            for (int w = 0; w < 16; ++w) s += lds[w * 7 + k];
            tot[k] = s;
        }
        double fl_a = tot[0], ca = tot[1], fl_o = tot[2], co = tot[3];
        double bsum = tot[4], sv = tot[5], sc = tot[6];
        double aspect  = (ca > 0.0) ? fl_a / fmax(ca, 1.0) : 0.0;
        double opinion = (co > 0.0) ? fl_o / fmax(co, 1.0) : 0.0;
        double senti   = sv / fmax(sc, 1.0);
        double bnd     = bsum / (double)((long long)NPOS * 2);
        out[0] = (float)(aspect + opinion + senti + 0.5 * bnd);
    }
}

extern "C" void kernel_launch(void* const* d_in, const int* in_sizes, int n_in,
                              void* d_out, int out_size, void* d_ws, size_t ws_size,
                              hipStream_t stream) {
    const float* a_logits = (const float*)d_in[0];   // (B,S,3)
    const float* o_logits = (const float*)d_in[1];   // (B,S,3)
    const float* s_logits = (const float*)d_in[2];   // (B,3)
    const float* b_logits = (const float*)d_in[3];   // (B,S,2)
    const int*   a_labels = (const int*)d_in[4];     // (B,S)
    const int*   o_labels = (const int*)d_in[5];     // (B,S)
    const int*   s_labels = (const int*)d_in[6];     // (B,)
    float* out = (float*)d_out;
    float* partial = (float*)d_ws;                   // 5 * 2048 floats = 40 KB

    main_kernel<<<BLOCKS, 256, 0, stream>>>(a_logits, o_logits, b_logits,
                                            a_labels, o_labels, partial);
    sent_final_kernel<<<1, 1024, 0, stream>>>(s_logits, s_labels, partial, out);
}